// Round 3
// baseline (1052.144 us; speedup 1.0000x reference)
//
#include <hip/hip_runtime.h>

#define NN 16
#define CC 192
#define TT 120
#define VV 100
#define NH 4

typedef __attribute__((ext_vector_type(4))) float  float4v;
typedef __attribute__((ext_vector_type(8))) short  short8;
typedef __attribute__((ext_vector_type(2))) int    int2v;

#define MFMA16(A,B,Cacc) __builtin_amdgcn_mfma_f32_16x16x32_bf16(A,B,Cacc,0,0,0)

union S8U { unsigned u[4]; short8 s; };

// truncating f32->bf16 pair pack: returns bf16(b)<<16 | bf16(a)  (1 v_perm)
__device__ __forceinline__ unsigned pk2(float a, float b) {
  union { float f; unsigned u; } x, y; x.f = a; y.f = b;
  return __builtin_amdgcn_perm(y.u, x.u, 0x07060302u);
}
__device__ __forceinline__ short b16t(float f) {
  union { float f; unsigned u; } x; x.f = f;
  return (short)(x.u >> 16);
}
// RNE (for one-time weight conversion)
__device__ __forceinline__ short f2b(float f) {
  union { float f; unsigned u; } x; x.f = f;
  unsigned r = x.u + 0x7fffu + ((x.u >> 16) & 1u);
  return (short)(r >> 16);
}

// ---------------- kernel 1: weights fp32 -> bf16, pre-swizzled into MFMA frag order ----------------
__global__ __launch_bounds__(256) void k_conv(const float* __restrict__ wq,
                                              const float* __restrict__ wk,
                                              const float* __restrict__ wp,
                                              short* __restrict__ wqF,
                                              short* __restrict__ wkF,
                                              short* __restrict__ wpF) {
  int i = blockIdx.x * 256 + threadIdx.x;   // grid 576 -> 147456
  if (i < CC*CC) {
    int o = i / CC, a = i % CC;
    int ct = o >> 4, l = o & 15, kc = a >> 5, q = (a & 31) >> 3, j = a & 7;
    int dst = ((ct*6 + kc)*64 + q*16 + l)*8 + j;
    wqF[dst] = f2b(wq[i]);
    wkF[dst] = f2b(wk[i]);
  }
  if (i < CC*CC*NH) {
    int o = i / (CC*NH), c2 = i % (CC*NH);
    int s = c2 / CC, cc = c2 % CC;
    int T = o >> 4, l = o & 15, kc = cc >> 5, q = (cc & 31) >> 3, j = cc & 7;
    int dst = (((s*12 + T)*6 + kc)*64 + q*16 + l)*8 + j;
    wpF[dst] = f2b(wp[i]);
  }
}

// ---------------- kernel 2a: QK projection, output in scores-fragment order ----------------
// grid 1920 = (n,t); 448 thr = 7 waves; wave w owns u-tile ut=w. No LDS, no barriers.
// Out layout Qf/Kf[n][s][ut(7)][kk(180)][lane(64)][j(8)] bf16, k = 48*t + c'.
// D-quad d[0..3] lands at 4 CONTIGUOUS k-slots -> single 8B packed store.
__global__ __launch_bounds__(448, 3) void k_qk(const float* __restrict__ xq,
                                               const float* __restrict__ xkv,
                                               const short* __restrict__ wqF,
                                               const short* __restrict__ wkF,
                                               const float* __restrict__ bq,
                                               const float* __restrict__ bk,
                                               short* __restrict__ Qf,
                                               short* __restrict__ Kf) {
  const int n = blockIdx.x / TT, t = blockIdx.x % TT;
  const int tid = threadIdx.x, w = tid >> 6, lane = tid & 63;
  const int q = lane >> 4, l15 = lane & 15;
  const int u = 16*w + l15, uc = (u < VV) ? u : (VV-1);
  const size_t ns0 = (size_t)n*NH;

  #pragma unroll 1
  for (int ph = 0; ph < 2; ++ph) {
    const float* xb   = (ph ? xkv : xq) + (size_t)n*CC*TT*VV + t*VV;
    const short* wF   = ph ? wkF : wqF;
    const float* bias = ph ? bk : bq;
    short*       Of   = ph ? Kf : Qf;

    // B-frags of x: lane holds x[c=32kc+8q+j][u]
    short8 xf[6];
    #pragma unroll
    for (int kc = 0; kc < 6; ++kc) {
      float f[8];
      #pragma unroll
      for (int j = 0; j < 8; ++j)
        f[j] = xb[(size_t)(32*kc + 8*q + j)*(TT*VV) + uc];
      S8U sv; sv.u[0]=pk2(f[0],f[1]); sv.u[1]=pk2(f[2],f[3]); sv.u[2]=pk2(f[4],f[5]); sv.u[3]=pk2(f[6],f[7]);
      xf[kc] = sv.s;
    }
    #pragma unroll
    for (int ct = 0; ct < 12; ++ct) {
      float4v d = (float4v){0.f,0.f,0.f,0.f};
      #pragma unroll
      for (int kc = 0; kc < 6; ++kc) {
        short8 wf = *(const short8*)&wF[((ct*6 + kc)*64 + lane)*8];
        d = MFMA16(wf, xf[kc], d);   // D row = o = 16ct+4q+r, col = u = 16w+l15
      }
      const float4v bv = *(const float4v*)&bias[16*ct + 4*q];
      const int sH = ct/3;
      const int kb = 48*t + 16*(ct - 3*sH);
      const int kq = kb + 4*q;                   // j2 in {0,4}; r=0..3 contiguous
      const int kk = kq >> 5, q2 = (kq >> 3) & 3, j2 = kq & 7;
      size_t base = ((((ns0 + sH)*7 + w)*180 + kk)*64 + (q2*16 + l15))*8 + j2;
      int2v pr;
      pr.x = (int)pk2(d[0] + bv[0], d[1] + bv[1]);
      pr.y = (int)pk2(d[2] + bv[2], d[3] + bv[3]);
      *(int2v*)&Of[base] = pr;
    }
  }
}

// ---------------- kernel 2b: scores GEMM over K=5760, v-split for occupancy ----------------
// grid 768 = ns*12 + kc*2 + vh; 448 thr = 7 waves; wave w owns u-tile, vh picks vt range.
__global__ __launch_bounds__(448, 4) void k_scores3(const short* __restrict__ Qf,
                                                    const short* __restrict__ Kf,
                                                    float* __restrict__ part2) {
  const int b = blockIdx.x;
  const int vh = b & 1, kc = (b >> 1) % 6, ns = b / 12;
  const int tid = threadIdx.x, w = tid >> 6, lane = tid & 63;
  const int q = lane >> 4, l15 = lane & 15;
  const short* Qb = Qf + (((size_t)ns*7 + w)*180 + kc*30)*512 + lane*8;
  const short* Kb = Kf + ((size_t)ns*7*180 + kc*30)*512 + lane*8;
  const int vt0 = vh ? 4 : 0, nvt = vh ? 3 : 4;

  float4v acc[4];
  #pragma unroll
  for (int j = 0; j < 4; ++j) acc[j] = (float4v){0.f,0.f,0.f,0.f};

  #pragma unroll 2
  for (int kk = 0; kk < 30; ++kk) {
    short8 aQ = *(const short8*)&Qb[(size_t)kk*512];
    #pragma unroll
    for (int j = 0; j < 4; ++j) {
      if (j < nvt) {
        short8 bK = *(const short8*)&Kb[((size_t)(vt0 + j)*180 + kk)*512];
        acc[j] = MFMA16(aQ, bK, acc[j]);   // D row = u = 16w+4q+r, col = v
      }
    }
  }
  #pragma unroll
  for (int j = 0; j < 4; ++j) {
    if (j < nvt) {
      size_t p2 = (((size_t)ns*6 + kc)*112 + 16*(vt0 + j) + l15)*112 + 16*w + 4*q;
      __builtin_nontemporal_store(acc[j], (float4v*)&part2[p2]);
    }
  }
}

// ---------------- kernel 3: 6-way reduce + tanh + alpha/ga -> attnT bf16 [n][s][v112][u128] ----------------
__global__ __launch_bounds__(256) void k_reduce2(const float* __restrict__ part2,
                                                 const float* __restrict__ alphas,
                                                 const float* __restrict__ ga,
                                                 short* __restrict__ attnT) {
  int bid = blockIdx.x;                 // 64*56 = 3584
  int ns = bid / 56, vc = bid % 56;
  int v = vc*2 + (threadIdx.x >> 7), u = threadIdx.x & 127;
  int s = ns & 3;
  float val = 0.f;
  if (v < VV && u < VV) {
    float sum = 0.f;
    #pragma unroll
    for (int kc = 0; kc < 6; ++kc)
      sum += __builtin_nontemporal_load(&part2[(((size_t)ns*6 + kc)*112 + v)*112 + u]);
    val = tanhf(sum * (1.f/5760.f)) * alphas[s] + ga[u*VV + v];
  }
  attnT[((size_t)ns*112 + v)*128 + u] = f2b(val);
}

// ---------------- fallback scores path (old) if workspace too small ----------------
__global__ __launch_bounds__(448, 2) void k_scoresB(const float* __restrict__ xq,
                                                    const float* __restrict__ xkv,
                                                    const short* __restrict__ wqF,
                                                    const short* __restrict__ wkF,
                                                    const float* __restrict__ bq,
                                                    const float* __restrict__ bk,
                                                    float* __restrict__ part) {
  __shared__ short QT[112*200];
  __shared__ short KT[112*56];
  const int n = blockIdx.x / 15, tc = blockIdx.x % 15;
  const int tid = threadIdx.x, w = tid >> 6, lane = tid & 63;
  const int q = lane >> 4, l15 = lane & 15;
  const int u = 16*w + l15, uc = (u < VV) ? u : (VV-1);
  float4v acc[NH][7];
  #pragma unroll
  for (int s = 0; s < NH; ++s)
    #pragma unroll
    for (int vt = 0; vt < 7; ++vt) acc[s][vt] = (float4v){0.f,0.f,0.f,0.f};
  const short8 z8 = {0,0,0,0,0,0,0,0};
  #pragma unroll 1
  for (int it = 0; it < 8; ++it) {
    const int t = tc*8 + it;
    short8 xf[6];
    #pragma unroll
    for (int kc = 0; kc < 6; ++kc) {
      float f[8];
      #pragma unroll
      for (int j = 0; j < 8; ++j)
        f[j] = xq[(n*CC + 32*kc + 8*q + j)*(TT*VV) + t*VV + uc];
      S8U sv; sv.u[0]=pk2(f[0],f[1]); sv.u[1]=pk2(f[2],f[3]); sv.u[2]=pk2(f[4],f[5]); sv.u[3]=pk2(f[6],f[7]);
      xf[kc] = sv.s;
    }
    #pragma unroll
    for (int ct = 0; ct < 12; ++ct) {
      float4v d = (float4v){0.f,0.f,0.f,0.f};
      #pragma unroll
      for (int kc = 0; kc < 6; ++kc) {
        short8 wf = *(const short8*)&wqF[((ct*6 + kc)*64 + q*16 + l15)*8];
        d = MFMA16(xf[kc], wf, d);
      }
      float bb = bq[16*ct + l15];
      #pragma unroll
      for (int r = 0; r < 4; ++r)
        QT[(16*w + 4*q + r)*200 + 16*ct + l15] = b16t(d[r] + bb);
    }
    short8 xg[6];
    #pragma unroll
    for (int kc = 0; kc < 6; ++kc) {
      float f[8];
      #pragma unroll
      for (int j = 0; j < 8; ++j)
        f[j] = xkv[(n*CC + 32*kc + 8*q + j)*(TT*VV) + t*VV + uc];
      S8U sv; sv.u[0]=pk2(f[0],f[1]); sv.u[1]=pk2(f[2],f[3]); sv.u[2]=pk2(f[4],f[5]); sv.u[3]=pk2(f[6],f[7]);
      xg[kc] = sv.s;
    }
    #pragma unroll 1
    for (int s = 0; s < NH; ++s) {
      #pragma unroll
      for (int ctk = 0; ctk < 3; ++ctk) {
        float4v d = (float4v){0.f,0.f,0.f,0.f};
        #pragma unroll
        for (int kc = 0; kc < 6; ++kc) {
          short8 wf = *(const short8*)&wkF[(((3*s + ctk)*6 + kc)*64 + q*16 + l15)*8];
          d = MFMA16(xg[kc], wf, d);
        }
        float bb = bk[48*s + 16*ctk + l15];
        #pragma unroll
        for (int r = 0; r < 4; ++r)
          KT[(16*w + 4*q + r)*56 + 16*ctk + l15] = b16t(d[r] + bb);
      }
      __syncthreads();
      #pragma unroll
      for (int kcp = 0; kcp < 2; ++kcp) {
        short8 aQ = z8;
        if (kcp == 0 || q < 2)
          aQ = *(const short8*)&QT[(16*w + l15)*200 + 48*s + 32*kcp + 8*q];
        #pragma unroll
        for (int vt = 0; vt < 7; ++vt) {
          short8 bK = z8;
          if (kcp == 0 || q < 2)
            bK = *(const short8*)&KT[(16*vt + l15)*56 + 32*kcp + 8*q];
          acc[s][vt] = MFMA16(aQ, bK, acc[s][vt]);
        }
      }
      __syncthreads();
    }
  }
  #pragma unroll
  for (int s = 0; s < NH; ++s)
    #pragma unroll
    for (int vt = 0; vt < 7; ++vt) {
      int v = 16*vt + l15;
      if (v < VV)
        __builtin_nontemporal_store(acc[s][vt],
          (float4v*)&part[(((n*15 + tc)*NH + s)*VV + v)*112 + 16*w + 4*q]);
    }
}

__global__ __launch_bounds__(256) void k_reduce(const float* __restrict__ part,
                                                const float* __restrict__ alphas,
                                                const float* __restrict__ ga,
                                                short* __restrict__ attnT) {
  int bid = blockIdx.x;
  int n = bid / 224, rem = bid % 224, s = rem / 56, vc = rem % 56;
  int v = vc*2 + (threadIdx.x >> 7), uu = threadIdx.x & 127;
  float val = 0.f;
  if (v < VV && uu < VV) {
    float sum = 0.f;
    for (int tcc = 0; tcc < 15; ++tcc)
      sum += __builtin_nontemporal_load(&part[(((n*15 + tcc)*NH + s)*VV + v)*112 + uu]);
    val = tanhf(sum * (1.f/5760.f)) * alphas[s] + ga[uu*VV + v];
  }
  attnT[((n*NH + s)*112 + v)*128 + uu] = f2b(val);
}

// ---------------- kernel 4: values-first fused attn-apply + out-proj ----------------
// grid 1920 = (n,t); 384 thr = 6 waves; wave w owns c-tiles / o-tiles {w, w+6}.
// xkv fragments hoisted into registers ONCE (s-independent) -> xkv read exactly once.
// Per head s: B1 per c-tile (y[7] regs), pack -> YT[v][c]; B2 out-proj from YT + wpF.
__global__ __launch_bounds__(384, 3) void k_outD(const float* __restrict__ xkv,
                                                 const short* __restrict__ wpF,
                                                 const short* __restrict__ attnT,
                                                 const float* __restrict__ bp,
                                                 float* __restrict__ out) {
  __shared__ short YT[112*200];      // [v][c] bf16, stride 200, 44800 B
  const int n = blockIdx.x / TT, t = blockIdx.x % TT;
  const int tid = threadIdx.x, w = tid >> 6, lane = tid & 63;
  const int q = lane >> 4, l15 = lane & 15;

  float4v accO[2][7];
  #pragma unroll
  for (int i = 0; i < 2; ++i)
    #pragma unroll
    for (int vt = 0; vt < 7; ++vt) accO[i][vt] = (float4v){0.f,0.f,0.f,0.f};

  // hoisted xkv A-frags: lane's row c = 16*(w+6i)+l15, k = u (contiguous)
  short8   xh[2][3];
  unsigned xt[2][2];
  #pragma unroll
  for (int i = 0; i < 2; ++i) {
    const float* xb = xkv + ((size_t)(n*CC + 16*(w + 6*i) + l15)*TT + t)*VV;
    #pragma unroll
    for (int ku = 0; ku < 3; ++ku) {
      const float4v A = *(const float4v*)(xb + 32*ku + 8*q);
      const float4v B = *(const float4v*)(xb + 32*ku + 8*q + 4);
      S8U sv; sv.u[0]=pk2(A[0],A[1]); sv.u[1]=pk2(A[2],A[3]);
      sv.u[2]=pk2(B[0],B[1]); sv.u[3]=pk2(B[2],B[3]);
      xh[i][ku] = sv.s;
    }
    if (q == 0) {               // u = 96..99 tail (u>=100 multiplied by zero attnT)
      const float4v A = *(const float4v*)(xb + 96);
      xt[i][0] = pk2(A[0],A[1]); xt[i][1] = pk2(A[2],A[3]);
    } else { xt[i][0] = 0u; xt[i][1] = 0u; }
  }

  #pragma unroll 1
  for (int s = 0; s < NH; ++s) {
    const short* aT = attnT + (size_t)((n*NH + s)*112)*128;
    float4v y[7];

    // ---- B1, c-tile i=0 (overlaps with other waves finishing prev B2) ----
    #pragma unroll
    for (int vt = 0; vt < 7; ++vt) y[vt] = (float4v){0.f,0.f,0.f,0.f};
    #pragma unroll
    for (int ku = 0; ku < 4; ++ku) {
      short8 xa;
      if (ku < 3) xa = xh[0][ku];
      else { S8U sv; sv.u[0]=xt[0][0]; sv.u[1]=xt[0][1]; sv.u[2]=0u; sv.u[3]=0u; xa = sv.s; }
      #pragma unroll
      for (int vt = 0; vt < 7; ++vt) {
        short8 bv = *(const short8*)&aT[(16*vt + l15)*128 + 32*ku + 8*q];
        y[vt] = MFMA16(xa, bv, y[vt]);
      }
    }
    __syncthreads();           // prev head's B2 done reading YT
    #pragma unroll
    for (int vt = 0; vt < 7; ++vt) {
      int2v pr; pr.x = (int)pk2(y[vt][0], y[vt][1]); pr.y = (int)pk2(y[vt][2], y[vt][3]);
      *(int2v*)&YT[(16*vt + l15)*200 + 16*w + 4*q] = pr;
    }

    // ---- B1, c-tile i=1 ----
    #pragma unroll
    for (int vt = 0; vt < 7; ++vt) y[vt] = (float4v){0.f,0.f,0.f,0.f};
    #pragma unroll
    for (int ku = 0; ku < 4; ++ku) {
      short8 xa;
      if (ku < 3) xa = xh[1][ku];
      else { S8U sv; sv.u[0]=xt[1][0]; sv.u[1]=xt[1][1]; sv.u[2]=0u; sv.u[3]=0u; xa = sv.s; }
      #pragma unroll
      for (int vt = 0; vt < 7; ++vt) {
        short8 bv = *(const short8*)&aT[(16*vt + l15)*128 + 32*ku + 8*q];
        y[vt] = MFMA16(xa, bv, y[vt]);
      }
    }
    #pragma unroll
    for (int vt = 0; vt < 7; ++vt) {
      int2v pr; pr.x = (int)pk2(y[vt][0], y[vt][1]); pr.y = (int)pk2(y[vt][2], y[vt][3]);
      *(int2v*)&YT[(16*vt + l15)*200 + 16*(w + 6) + 4*q] = pr;
    }
    __syncthreads();           // YT(s) complete

    // ---- B2: out-proj, contract over c (6 chunks of 32) ----
    #pragma unroll
    for (int kc2 = 0; kc2 < 6; ++kc2) {
      short8 ya[7];
      #pragma unroll
      for (int vt = 0; vt < 7; ++vt)
        ya[vt] = *(const short8*)&YT[(16*vt + l15)*200 + 32*kc2 + 8*q];
      #pragma unroll
      for (int i = 0; i < 2; ++i) {
        short8 wf = *(const short8*)&wpF[(((s*12 + (w + 6*i))*6 + kc2)*64 + q*16 + l15)*8];
        #pragma unroll
        for (int vt = 0; vt < 7; ++vt)
          accO[i][vt] = MFMA16(ya[vt], wf, accO[i][vt]);
      }
    }
  }

  // epilogue: + bp, regular stores (let L2 write-combine full lines)
  #pragma unroll
  for (int i = 0; i < 2; ++i) {
    int o = 16*(w + 6*i) + l15;
    float b = bp[o];
    #pragma unroll
    for (int vt = 0; vt < 7; ++vt) {
      int v0 = 16*vt + 4*q;
      if (v0 < VV) {
        float4v r = accO[i][vt];
        r[0] += b; r[1] += b; r[2] += b; r[3] += b;
        *(float4v*)&out[((size_t)(n*CC + o)*TT + t)*VV + v0] = r;
      }
    }
  }
}

extern "C" void kernel_launch(void* const* d_in, const int* in_sizes, int n_in,
                              void* d_out, int out_size, void* d_ws, size_t ws_size,
                              hipStream_t stream) {
  const float* xq     = (const float*)d_in[0];
  const float* xkv    = (const float*)d_in[1];
  const float* wq     = (const float*)d_in[2];
  const float* bq     = (const float*)d_in[3];
  const float* wk     = (const float*)d_in[4];
  const float* bk     = (const float*)d_in[5];
  const float* wp     = (const float*)d_in[6];
  const float* bp     = (const float*)d_in[7];
  const float* alphas = (const float*)d_in[8];
  const float* ga     = (const float*)d_in[9];
  float* out = (float*)d_out;
  char*  ws  = (char*)d_ws;

  // ws layout (new path):
  // wqF 0..73728 | wkF ..147456 | wpF ..442368 | attnT ..2277376 |
  // Qf ..84852736 | Kf ..167428096 | part2 ..186695680
  short* wqF   = (short*)(ws);
  short* wkF   = (short*)(ws + 73728);
  short* wpF   = (short*)(ws + 147456);
  short* attnT = (short*)(ws + 442368);

  hipLaunchKernelGGL(k_conv, dim3(576), dim3(256), 0, stream, wq, wk, wp, wqF, wkF, wpF);

  if (ws_size >= 186695680ULL) {
    short* Qf    = (short*)(ws + 2277376);
    short* Kf    = (short*)(ws + 84852736ULL);
    float* part2 = (float*)(ws + 167428096ULL);
    hipLaunchKernelGGL(k_qk,      dim3(1920), dim3(448), 0, stream, xq, xkv, wqF, wkF, bq, bk, Qf, Kf);
    hipLaunchKernelGGL(k_scores3, dim3(768),  dim3(448), 0, stream, Qf, Kf, part2);
    hipLaunchKernelGGL(k_reduce2, dim3(3584), dim3(256), 0, stream, part2, alphas, ga, attnT);
  } else {
    float* part = (float*)(ws + 2277376);
    hipLaunchKernelGGL(k_scoresB, dim3(240),  dim3(448), 0, stream, xq, xkv, wqF, wkF, bq, bk, part);
    hipLaunchKernelGGL(k_reduce,  dim3(3584), dim3(256), 0, stream, part, alphas, ga, attnT);
  }

  hipLaunchKernelGGL(k_outD, dim3(1920), dim3(384), 0, stream, xkv, wpF, attnT, bp, out);
}

// Round 4
// 800.676 us; speedup vs baseline: 1.3141x; 1.3141x over previous
//
#include <hip/hip_runtime.h>

#define NN 16
#define CC 192
#define TT 120
#define VV 100
#define NH 4

typedef __attribute__((ext_vector_type(4))) float  float4v;
typedef __attribute__((ext_vector_type(8))) short  short8;
typedef __attribute__((ext_vector_type(2))) int    int2v;

#define MFMA16(A,B,Cacc) __builtin_amdgcn_mfma_f32_16x16x32_bf16(A,B,Cacc,0,0,0)

union S8U { unsigned u[4]; short8 s; };

// truncating f32->bf16 pair pack: returns bf16(b)<<16 | bf16(a)  (1 v_perm)
__device__ __forceinline__ unsigned pk2(float a, float b) {
  union { float f; unsigned u; } x, y; x.f = a; y.f = b;
  return __builtin_amdgcn_perm(y.u, x.u, 0x07060302u);
}
__device__ __forceinline__ short b16t(float f) {
  union { float f; unsigned u; } x; x.f = f;
  return (short)(x.u >> 16);
}
// RNE (for one-time weight conversion)
__device__ __forceinline__ short f2b(float f) {
  union { float f; unsigned u; } x; x.f = f;
  unsigned r = x.u + 0x7fffu + ((x.u >> 16) & 1u);
  return (short)(r >> 16);
}

// ---------------- kernel 1: weights fp32 -> bf16, pre-swizzled into MFMA frag order ----------------
__global__ __launch_bounds__(256) void k_conv(const float* __restrict__ wq,
                                              const float* __restrict__ wk,
                                              const float* __restrict__ wp,
                                              short* __restrict__ wqF,
                                              short* __restrict__ wkF,
                                              short* __restrict__ wpF) {
  int i = blockIdx.x * 256 + threadIdx.x;   // grid 576 -> 147456
  if (i < CC*CC) {
    int o = i / CC, a = i % CC;
    int ct = o >> 4, l = o & 15, kc = a >> 5, q = (a & 31) >> 3, j = a & 7;
    int dst = ((ct*6 + kc)*64 + q*16 + l)*8 + j;
    wqF[dst] = f2b(wq[i]);
    wkF[dst] = f2b(wk[i]);
  }
  if (i < CC*CC*NH) {
    int o = i / (CC*NH), c2 = i % (CC*NH);
    int s = c2 / CC, cc = c2 % CC;
    int T = o >> 4, l = o & 15, kc = cc >> 5, q = (cc & 31) >> 3, j = cc & 7;
    int dst = (((s*12 + T)*6 + kc)*64 + q*16 + l)*8 + j;
    wpF[dst] = f2b(wp[i]);
  }
}

// ---------------- kernel 2a: QK projection, output in scores-fragment order ----------------
// grid 1920 = (n,t); 448 thr = 7 waves; wave w owns u-tile ut=w. No LDS, no barriers.
// launch_bounds(448,4): VGPR<=128 so TWO 7-wave blocks fit per CU (14 waves) -- (448,3)
// allowed only 12 waves/CU => a single block resident => gather-latency starvation.
__global__ __launch_bounds__(448, 4) void k_qk(const float* __restrict__ xq,
                                               const float* __restrict__ xkv,
                                               const short* __restrict__ wqF,
                                               const short* __restrict__ wkF,
                                               const float* __restrict__ bq,
                                               const float* __restrict__ bk,
                                               short* __restrict__ Qf,
                                               short* __restrict__ Kf) {
  const int n = blockIdx.x / TT, t = blockIdx.x % TT;
  const int tid = threadIdx.x, w = tid >> 6, lane = tid & 63;
  const int q = lane >> 4, l15 = lane & 15;
  const int u = 16*w + l15, uc = (u < VV) ? u : (VV-1);
  const size_t ns0 = (size_t)n*NH;

  #pragma unroll 1
  for (int ph = 0; ph < 2; ++ph) {
    const float* xb   = (ph ? xkv : xq) + (size_t)n*CC*TT*VV + t*VV;
    const short* wF   = ph ? wkF : wqF;
    const float* bias = ph ? bk : bq;
    short*       Of   = ph ? Kf : Qf;

    // B-frags of x: lane holds x[c=32kc+8q+j][u]
    short8 xf[6];
    #pragma unroll
    for (int kc = 0; kc < 6; ++kc) {
      float f[8];
      #pragma unroll
      for (int j = 0; j < 8; ++j)
        f[j] = xb[(size_t)(32*kc + 8*q + j)*(TT*VV) + uc];
      S8U sv; sv.u[0]=pk2(f[0],f[1]); sv.u[1]=pk2(f[2],f[3]); sv.u[2]=pk2(f[4],f[5]); sv.u[3]=pk2(f[6],f[7]);
      xf[kc] = sv.s;
    }
    #pragma unroll
    for (int ct = 0; ct < 12; ++ct) {
      float4v d = (float4v){0.f,0.f,0.f,0.f};
      #pragma unroll
      for (int kc = 0; kc < 6; ++kc) {
        short8 wf = *(const short8*)&wF[((ct*6 + kc)*64 + lane)*8];
        d = MFMA16(wf, xf[kc], d);   // D row = o = 16ct+4q+r, col = u = 16w+l15
      }
      const float4v bv = *(const float4v*)&bias[16*ct + 4*q];
      const int sH = ct/3;
      const int kb = 48*t + 16*(ct - 3*sH);
      const int kq = kb + 4*q;                   // j2 in {0,4}; r=0..3 contiguous
      const int kk = kq >> 5, q2 = (kq >> 3) & 3, j2 = kq & 7;
      size_t base = ((((ns0 + sH)*7 + w)*180 + kk)*64 + (q2*16 + l15))*8 + j2;
      int2v pr;
      pr.x = (int)pk2(d[0] + bv[0], d[1] + bv[1]);
      pr.y = (int)pk2(d[2] + bv[2], d[3] + bv[3]);
      *(int2v*)&Of[base] = pr;
    }
  }
}

// ---------------- kernel 2b: scores GEMM over K=5760, v-split for occupancy ----------------
__global__ __launch_bounds__(448, 4) void k_scores3(const short* __restrict__ Qf,
                                                    const short* __restrict__ Kf,
                                                    float* __restrict__ part2) {
  const int b = blockIdx.x;
  const int vh = b & 1, kc = (b >> 1) % 6, ns = b / 12;
  const int tid = threadIdx.x, w = tid >> 6, lane = tid & 63;
  const int q = lane >> 4, l15 = lane & 15;
  const short* Qb = Qf + (((size_t)ns*7 + w)*180 + kc*30)*512 + lane*8;
  const short* Kb = Kf + ((size_t)ns*7*180 + kc*30)*512 + lane*8;
  const int vt0 = vh ? 4 : 0, nvt = vh ? 3 : 4;

  float4v acc[4];
  #pragma unroll
  for (int j = 0; j < 4; ++j) acc[j] = (float4v){0.f,0.f,0.f,0.f};

  #pragma unroll 2
  for (int kk = 0; kk < 30; ++kk) {
    short8 aQ = *(const short8*)&Qb[(size_t)kk*512];
    #pragma unroll
    for (int j = 0; j < 4; ++j) {
      if (j < nvt) {
        short8 bK = *(const short8*)&Kb[((size_t)(vt0 + j)*180 + kk)*512];
        acc[j] = MFMA16(aQ, bK, acc[j]);   // D row = u = 16w+4q+r, col = v
      }
    }
  }
  #pragma unroll
  for (int j = 0; j < 4; ++j) {
    if (j < nvt) {
      size_t p2 = (((size_t)ns*6 + kc)*112 + 16*(vt0 + j) + l15)*112 + 16*w + 4*q;
      __builtin_nontemporal_store(acc[j], (float4v*)&part2[p2]);
    }
  }
}

// ---------------- kernel 3: 6-way reduce + tanh + alpha/ga -> attnT bf16 [n][s][v112][u128] ----------------
__global__ __launch_bounds__(256) void k_reduce2(const float* __restrict__ part2,
                                                 const float* __restrict__ alphas,
                                                 const float* __restrict__ ga,
                                                 short* __restrict__ attnT) {
  int bid = blockIdx.x;                 // 64*56 = 3584
  int ns = bid / 56, vc = bid % 56;
  int v = vc*2 + (threadIdx.x >> 7), u = threadIdx.x & 127;
  int s = ns & 3;
  float val = 0.f;
  if (v < VV && u < VV) {
    float sum = 0.f;
    #pragma unroll
    for (int kc = 0; kc < 6; ++kc)
      sum += __builtin_nontemporal_load(&part2[(((size_t)ns*6 + kc)*112 + v)*112 + u]);
    val = tanhf(sum * (1.f/5760.f)) * alphas[s] + ga[u*VV + v];
  }
  attnT[((size_t)ns*112 + v)*128 + u] = f2b(val);
}

// ---------------- fallback scores path (old) if workspace too small ----------------
__global__ __launch_bounds__(448, 2) void k_scoresB(const float* __restrict__ xq,
                                                    const float* __restrict__ xkv,
                                                    const short* __restrict__ wqF,
                                                    const short* __restrict__ wkF,
                                                    const float* __restrict__ bq,
                                                    const float* __restrict__ bk,
                                                    float* __restrict__ part) {
  __shared__ short QT[112*200];
  __shared__ short KT[112*56];
  const int n = blockIdx.x / 15, tc = blockIdx.x % 15;
  const int tid = threadIdx.x, w = tid >> 6, lane = tid & 63;
  const int q = lane >> 4, l15 = lane & 15;
  const int u = 16*w + l15, uc = (u < VV) ? u : (VV-1);
  float4v acc[NH][7];
  #pragma unroll
  for (int s = 0; s < NH; ++s)
    #pragma unroll
    for (int vt = 0; vt < 7; ++vt) acc[s][vt] = (float4v){0.f,0.f,0.f,0.f};
  const short8 z8 = {0,0,0,0,0,0,0,0};
  #pragma unroll 1
  for (int it = 0; it < 8; ++it) {
    const int t = tc*8 + it;
    short8 xf[6];
    #pragma unroll
    for (int kc = 0; kc < 6; ++kc) {
      float f[8];
      #pragma unroll
      for (int j = 0; j < 8; ++j)
        f[j] = xq[(n*CC + 32*kc + 8*q + j)*(TT*VV) + t*VV + uc];
      S8U sv; sv.u[0]=pk2(f[0],f[1]); sv.u[1]=pk2(f[2],f[3]); sv.u[2]=pk2(f[4],f[5]); sv.u[3]=pk2(f[6],f[7]);
      xf[kc] = sv.s;
    }
    #pragma unroll
    for (int ct = 0; ct < 12; ++ct) {
      float4v d = (float4v){0.f,0.f,0.f,0.f};
      #pragma unroll
      for (int kc = 0; kc < 6; ++kc) {
        short8 wf = *(const short8*)&wqF[((ct*6 + kc)*64 + q*16 + l15)*8];
        d = MFMA16(xf[kc], wf, d);
      }
      float bb = bq[16*ct + l15];
      #pragma unroll
      for (int r = 0; r < 4; ++r)
        QT[(16*w + 4*q + r)*200 + 16*ct + l15] = b16t(d[r] + bb);
    }
    short8 xg[6];
    #pragma unroll
    for (int kc = 0; kc < 6; ++kc) {
      float f[8];
      #pragma unroll
      for (int j = 0; j < 8; ++j)
        f[j] = xkv[(n*CC + 32*kc + 8*q + j)*(TT*VV) + t*VV + uc];
      S8U sv; sv.u[0]=pk2(f[0],f[1]); sv.u[1]=pk2(f[2],f[3]); sv.u[2]=pk2(f[4],f[5]); sv.u[3]=pk2(f[6],f[7]);
      xg[kc] = sv.s;
    }
    #pragma unroll 1
    for (int s = 0; s < NH; ++s) {
      #pragma unroll
      for (int ctk = 0; ctk < 3; ++ctk) {
        float4v d = (float4v){0.f,0.f,0.f,0.f};
        #pragma unroll
        for (int kc = 0; kc < 6; ++kc) {
          short8 wf = *(const short8*)&wkF[(((3*s + ctk)*6 + kc)*64 + q*16 + l15)*8];
          d = MFMA16(xg[kc], wf, d);
        }
        float bb = bk[48*s + 16*ctk + l15];
        #pragma unroll
        for (int r = 0; r < 4; ++r)
          KT[(16*w + 4*q + r)*56 + 16*ctk + l15] = b16t(d[r] + bb);
      }
      __syncthreads();
      #pragma unroll
      for (int kcp = 0; kcp < 2; ++kcp) {
        short8 aQ = z8;
        if (kcp == 0 || q < 2)
          aQ = *(const short8*)&QT[(16*w + l15)*200 + 48*s + 32*kcp + 8*q];
        #pragma unroll
        for (int vt = 0; vt < 7; ++vt) {
          short8 bK = z8;
          if (kcp == 0 || q < 2)
            bK = *(const short8*)&KT[(16*vt + l15)*56 + 32*kcp + 8*q];
          acc[s][vt] = MFMA16(aQ, bK, acc[s][vt]);
        }
      }
      __syncthreads();
    }
  }
  #pragma unroll
  for (int s = 0; s < NH; ++s)
    #pragma unroll
    for (int vt = 0; vt < 7; ++vt) {
      int v = 16*vt + l15;
      if (v < VV)
        __builtin_nontemporal_store(acc[s][vt],
          (float4v*)&part[(((n*15 + tc)*NH + s)*VV + v)*112 + 16*w + 4*q]);
    }
}

__global__ __launch_bounds__(256) void k_reduce(const float* __restrict__ part,
                                                const float* __restrict__ alphas,
                                                const float* __restrict__ ga,
                                                short* __restrict__ attnT) {
  int bid = blockIdx.x;
  int n = bid / 224, rem = bid % 224, s = rem / 56, vc = rem % 56;
  int v = vc*2 + (threadIdx.x >> 7), uu = threadIdx.x & 127;
  float val = 0.f;
  if (v < VV && uu < VV) {
    float sum = 0.f;
    for (int tcc = 0; tcc < 15; ++tcc)
      sum += __builtin_nontemporal_load(&part[(((n*15 + tcc)*NH + s)*VV + v)*112 + uu]);
    val = tanhf(sum * (1.f/5760.f)) * alphas[s] + ga[uu*VV + v];
  }
  attnT[((n*NH + s)*112 + v)*128 + uu] = f2b(val);
}

// ---------------- kernel 4: values-first fused attn-apply + out-proj (k_outC structure +
// hoisted xkv + streamed-YT barrier placement) ----------------
// grid 1920 = (n,t); 256 thr = 4 waves; wave w owns c-/o-tiles {w, w+4, w+8}.
// Head loop: [barrier: prev B2 readers done] -> B1 per vt: 3 c-tiles share each bv load
// (1 global load : 3 MFMA), y-quads written to YT IMMEDIATELY (only 12 live B1 regs)
// -> [barrier: YT complete] -> B2 out-proj. xkv frags hoisted once per block.
__global__ __launch_bounds__(256, 2) void k_outE(const float* __restrict__ xkv,
                                                 const short* __restrict__ wpF,
                                                 const short* __restrict__ attnT,
                                                 const float* __restrict__ bp,
                                                 float* __restrict__ out) {
  __shared__ short YT[112*200];      // [v][c] bf16, stride 200 (2-way banks), 44800 B
  const int n = blockIdx.x / TT, t = blockIdx.x % TT;
  const int tid = threadIdx.x, w = tid >> 6, lane = tid & 63;
  const int q = lane >> 4, l15 = lane & 15;

  float4v accO[3][7];
  #pragma unroll
  for (int i = 0; i < 3; ++i)
    #pragma unroll
    for (int vt = 0; vt < 7; ++vt) accO[i][vt] = (float4v){0.f,0.f,0.f,0.f};

  // hoisted xkv A-frags (s-independent): lane's row c = 16*(w+4i)+l15, k = u contiguous
  short8   xh[3][3];
  unsigned xt3[3][2];
  #pragma unroll
  for (int i = 0; i < 3; ++i) {
    const float* xb = xkv + ((size_t)(n*CC + 16*(w + 4*i) + l15)*TT + t)*VV;
    #pragma unroll
    for (int ku = 0; ku < 3; ++ku) {
      const float4v A = *(const float4v*)(xb + 32*ku + 8*q);
      const float4v B = *(const float4v*)(xb + 32*ku + 8*q + 4);
      S8U sv; sv.u[0]=pk2(A[0],A[1]); sv.u[1]=pk2(A[2],A[3]);
      sv.u[2]=pk2(B[0],B[1]); sv.u[3]=pk2(B[2],B[3]);
      xh[i][ku] = sv.s;
    }
    if (q == 0) {               // u = 96..99 tail (attnT rows u>=100 are zero)
      const float4v A = *(const float4v*)(xb + 96);
      xt3[i][0] = pk2(A[0],A[1]); xt3[i][1] = pk2(A[2],A[3]);
    } else { xt3[i][0] = 0u; xt3[i][1] = 0u; }
  }

  #pragma unroll 1
  for (int s = 0; s < NH; ++s) {
    const short* aT = attnT + (size_t)((n*NH + s)*112)*128;

    __syncthreads();           // prev head's B2 done reading YT -> safe to stream writes
    #pragma unroll
    for (int vt = 0; vt < 7; ++vt) {
      float4v y0 = (float4v){0.f,0.f,0.f,0.f};
      float4v y1 = y0, y2 = y0;
      #pragma unroll
      for (int ku = 0; ku < 4; ++ku) {
        short8 bv = *(const short8*)&aT[(16*vt + l15)*128 + 32*ku + 8*q];
        short8 a0, a1, a2;
        if (ku < 3) { a0 = xh[0][ku]; a1 = xh[1][ku]; a2 = xh[2][ku]; }
        else {
          S8U s0, s1, s2;
          s0.u[0]=xt3[0][0]; s0.u[1]=xt3[0][1]; s0.u[2]=0u; s0.u[3]=0u;
          s1.u[0]=xt3[1][0]; s1.u[1]=xt3[1][1]; s1.u[2]=0u; s1.u[3]=0u;
          s2.u[0]=xt3[2][0]; s2.u[1]=xt3[2][1]; s2.u[2]=0u; s2.u[3]=0u;
          a0 = s0.s; a1 = s1.s; a2 = s2.s;
        }
        y0 = MFMA16(a0, bv, y0);
        y1 = MFMA16(a1, bv, y1);
        y2 = MFMA16(a2, bv, y2);
      }
      // D: col v = l15 (+16vt), row c = 4q+r (+16*(w+4i)) -> pack to YT[v][c] now
      int2v p0; p0.x = (int)pk2(y0[0], y0[1]); p0.y = (int)pk2(y0[2], y0[3]);
      int2v p1; p1.x = (int)pk2(y1[0], y1[1]); p1.y = (int)pk2(y1[2], y1[3]);
      int2v p2; p2.x = (int)pk2(y2[0], y2[1]); p2.y = (int)pk2(y2[2], y2[3]);
      *(int2v*)&YT[(16*vt + l15)*200 + 16*w + 4*q]       = p0;
      *(int2v*)&YT[(16*vt + l15)*200 + 16*(w + 4) + 4*q] = p1;
      *(int2v*)&YT[(16*vt + l15)*200 + 16*(w + 8) + 4*q] = p2;
    }
    __syncthreads();           // YT(s) complete

    // ---- B2: out-proj, contract over c (6 chunks of 32) ----
    #pragma unroll
    for (int kc2 = 0; kc2 < 6; ++kc2) {
      short8 ya[7];
      #pragma unroll
      for (int vt = 0; vt < 7; ++vt)
        ya[vt] = *(const short8*)&YT[(16*vt + l15)*200 + 32*kc2 + 8*q];
      #pragma unroll
      for (int i = 0; i < 3; ++i) {
        short8 wf = *(const short8*)&wpF[(((s*12 + (w + 4*i))*6 + kc2)*64 + q*16 + l15)*8];
        #pragma unroll
        for (int vt = 0; vt < 7; ++vt)
          accO[i][vt] = MFMA16(ya[vt], wf, accO[i][vt]);
      }
    }
  }

  // epilogue: + bp, regular stores (L2 write-combines full lines; verified round 3)
  #pragma unroll
  for (int i = 0; i < 3; ++i) {
    int o = 16*(w + 4*i) + l15;
    float b = bp[o];
    #pragma unroll
    for (int vt = 0; vt < 7; ++vt) {
      int v0 = 16*vt + 4*q;
      if (v0 < VV) {
        float4v r = accO[i][vt];
        r[0] += b; r[1] += b; r[2] += b; r[3] += b;
        *(float4v*)&out[((size_t)(n*CC + o)*TT + t)*VV + v0] = r;
      }
    }
  }
}

extern "C" void kernel_launch(void* const* d_in, const int* in_sizes, int n_in,
                              void* d_out, int out_size, void* d_ws, size_t ws_size,
                              hipStream_t stream) {
  const float* xq     = (const float*)d_in[0];
  const float* xkv    = (const float*)d_in[1];
  const float* wq     = (const float*)d_in[2];
  const float* bq     = (const float*)d_in[3];
  const float* wk     = (const float*)d_in[4];
  const float* bk     = (const float*)d_in[5];
  const float* wp     = (const float*)d_in[6];
  const float* bp     = (const float*)d_in[7];
  const float* alphas = (const float*)d_in[8];
  const float* ga     = (const float*)d_in[9];
  float* out = (float*)d_out;
  char*  ws  = (char*)d_ws;

  // ws layout (new path):
  // wqF 0..73728 | wkF ..147456 | wpF ..442368 | attnT ..2277376 |
  // Qf ..84852736 | Kf ..167428096 | part2 ..186695680
  short* wqF   = (short*)(ws);
  short* wkF   = (short*)(ws + 73728);
  short* wpF   = (short*)(ws + 147456);
  short* attnT = (short*)(ws + 442368);

  hipLaunchKernelGGL(k_conv, dim3(576), dim3(256), 0, stream, wq, wk, wp, wqF, wkF, wpF);

  if (ws_size >= 186695680ULL) {
    short* Qf    = (short*)(ws + 2277376);
    short* Kf    = (short*)(ws + 84852736ULL);
    float* part2 = (float*)(ws + 167428096ULL);
    hipLaunchKernelGGL(k_qk,      dim3(1920), dim3(448), 0, stream, xq, xkv, wqF, wkF, bq, bk, Qf, Kf);
    hipLaunchKernelGGL(k_scores3, dim3(768),  dim3(448), 0, stream, Qf, Kf, part2);
    hipLaunchKernelGGL(k_reduce2, dim3(3584), dim3(256), 0, stream, part2, alphas, ga, attnT);
  } else {
    float* part = (float*)(ws + 2277376);
    hipLaunchKernelGGL(k_scoresB, dim3(240),  dim3(448), 0, stream, xq, xkv, wqF, wkF, bq, bk, part);
    hipLaunchKernelGGL(k_reduce,  dim3(3584), dim3(256), 0, stream, part, alphas, ga, attnT);
  }

  hipLaunchKernelGGL(k_outE, dim3(1920), dim3(256), 0, stream, xkv, wpF, attnT, bp, out);
}